// Round 4
// baseline (247.111 us; speedup 1.0000x reference)
//
#include <hip/hip_runtime.h>
#include <math.h>

// BertBidafAttention B=16, CL=512, QL=64, H=768
//   u[b] = q[b]@W (split-bf16 MFMA);  beta = q.bias
//   s[b] = c[b]@u[b]^T + beta (split-bf16 MFMA, fused row-softmax -> s1 bf16)
//   s2t  = softmax_c(s)^T -> bf16 [b][q][c]
//   tt   = (s2^T @ c)^T   -> bf16 [b][h][q]
//   out  = [c, a, c*a, c*bvec]; a = s1@q, bvec = s1@t  (bf16 MFMA, transposed D for float4 stores)

#define B_  16
#define CL_ 512
#define QL_ 64
#define H_  768
#define M_  (B_ * CL_)   // 8192

typedef __attribute__((ext_vector_type(8))) short s8v;
typedef __attribute__((ext_vector_type(4))) float f4v;

__device__ __forceinline__ unsigned short bf16_rne(float x) {
    unsigned int u = __float_as_uint(x);
    u += 0x7fffu + ((u >> 16) & 1u);
    return (unsigned short)(u >> 16);
}
__device__ __forceinline__ float bf16_f(unsigned short h) {
    return __uint_as_float((unsigned int)h << 16);
}
__device__ __forceinline__ void split2(float x, unsigned short& h, unsigned short& l) {
    h = bf16_rne(x);
    l = bf16_rne(x - bf16_f(h));
}

// ---------- K1: W[d][h] -> wt[h][d] split bf16 ----------
__global__ __launch_bounds__(256) void k_tw(const float* __restrict__ W,
    unsigned short* __restrict__ wth, unsigned short* __restrict__ wtl)
{
    __shared__ float tile[64][68];
    const int d0 = blockIdx.x * 64, h0 = blockIdx.y * 64;
    const int t = threadIdx.x;
    const int r = t >> 4, c4 = (t & 15) * 4;
#pragma unroll
    for (int i = 0; i < 4; ++i)
        *(float4*)&tile[r + 16 * i][c4] = *(const float4*)&W[(size_t)(d0 + r + 16 * i) * H_ + h0 + c4];
    __syncthreads();
#pragma unroll
    for (int i = 0; i < 4; ++i) {
        int hr = r + 16 * i;
        ushort4 hh, ll;
        split2(tile[c4 + 0][hr], hh.x, ll.x);
        split2(tile[c4 + 1][hr], hh.y, ll.y);
        split2(tile[c4 + 2][hr], hh.z, ll.z);
        split2(tile[c4 + 3][hr], hh.w, ll.w);
        *(ushort4*)&wth[(size_t)(h0 + hr) * H_ + d0 + c4] = hh;
        *(ushort4*)&wtl[(size_t)(h0 + hr) * H_ + d0 + c4] = ll;
    }
}

// ---------- K2: q[b][qr][h] -> qt[b][h][qr] bf16 ----------
__global__ __launch_bounds__(256) void k_tq(const float* __restrict__ q,
    unsigned short* __restrict__ qt)
{
    __shared__ float tile[64][68];
    const int h0 = blockIdx.x * 64, b = blockIdx.y;
    const int t = threadIdx.x;
    const int r = t >> 4, c4 = (t & 15) * 4;
#pragma unroll
    for (int i = 0; i < 4; ++i)
        *(float4*)&tile[r + 16 * i][c4] = *(const float4*)&q[(size_t)(b * QL_ + r + 16 * i) * H_ + h0 + c4];
    __syncthreads();
#pragma unroll
    for (int i = 0; i < 4; ++i) {
        int hr = r + 16 * i;
        ushort4 hh;
        hh.x = bf16_rne(tile[c4 + 0][hr]);
        hh.y = bf16_rne(tile[c4 + 1][hr]);
        hh.z = bf16_rne(tile[c4 + 2][hr]);
        hh.w = bf16_rne(tile[c4 + 3][hr]);
        *(ushort4*)&qt[((size_t)b * H_ + h0 + hr) * QL_ + c4] = hh;
    }
}

// ---------- K3: u = q @ W (split-bf16), out split ----------
__global__ __launch_bounds__(256) void k_u(const float* __restrict__ q,
    const unsigned short* __restrict__ wth, const unsigned short* __restrict__ wtl,
    unsigned short* __restrict__ uh, unsigned short* __restrict__ ul)
{
    const int m0 = blockIdx.x * 64, n0 = blockIdx.y * 64;
    const int t = threadIdx.x, w = t >> 6, lane = t & 63;
    const int fm = lane & 15, quad = lane >> 4;
    const int mrow = m0 + w * 16 + fm;
    f4v acc[4];
#pragma unroll
    for (int j = 0; j < 4; ++j) acc[j] = (f4v){0.f, 0.f, 0.f, 0.f};
    for (int k0 = 0; k0 < H_; k0 += 32) {
        const float* ap = &q[(size_t)mrow * H_ + k0 + quad * 8];
        float4 a0 = *(const float4*)ap, a1 = *(const float4*)(ap + 4);
        float xs[8] = {a0.x, a0.y, a0.z, a0.w, a1.x, a1.y, a1.z, a1.w};
        s8v fah, fal;
#pragma unroll
        for (int j = 0; j < 8; ++j) { unsigned short h, l; split2(xs[j], h, l); fah[j] = (short)h; fal[j] = (short)l; }
#pragma unroll
        for (int tn = 0; tn < 4; ++tn) {
            const size_t bo = (size_t)(n0 + tn * 16 + fm) * H_ + k0 + quad * 8;
            s8v bh = *(const s8v*)&wth[bo];
            s8v bl = *(const s8v*)&wtl[bo];
            acc[tn] = __builtin_amdgcn_mfma_f32_16x16x32_bf16(fah, bh, acc[tn], 0, 0, 0);
            acc[tn] = __builtin_amdgcn_mfma_f32_16x16x32_bf16(fah, bl, acc[tn], 0, 0, 0);
            acc[tn] = __builtin_amdgcn_mfma_f32_16x16x32_bf16(fal, bh, acc[tn], 0, 0, 0);
        }
    }
#pragma unroll
    for (int tn = 0; tn < 4; ++tn) {
        const int col = n0 + tn * 16 + fm;
#pragma unroll
        for (int r = 0; r < 4; ++r) {
            const int row = m0 + w * 16 + quad * 4 + r;
            unsigned short h, l; split2(acc[tn][r], h, l);
            uh[(size_t)row * H_ + col] = h;
            ul[(size_t)row * H_ + col] = l;
        }
    }
}

// ---------- K4: beta[row] = bias . q[row] ----------
__global__ __launch_bounds__(256) void k_beta(const float* __restrict__ q,
    const float* __restrict__ bias, float* __restrict__ beta)
{
    const int row = blockIdx.x * 4 + (threadIdx.x >> 6);
    const int lane = threadIdx.x & 63;
    float p = 0.f;
    for (int d = lane; d < H_; d += 64) p = fmaf(bias[d], q[(size_t)row * H_ + d], p);
#pragma unroll
    for (int o = 32; o; o >>= 1) p += __shfl_xor(p, o);
    if (lane == 0) beta[row] = p;
}

// ---------- K5: s = c@u^T + beta (split-bf16) + fused row softmax -> s1 ----------
// grid 128; block = 64 c-rows; each wave: 16 unique rows x all 64 q cols.
__global__ __launch_bounds__(256) void k_s(const float* __restrict__ c,
    const unsigned short* __restrict__ uh, const unsigned short* __restrict__ ul,
    const float* __restrict__ beta, const int* __restrict__ q_mask,
    float* __restrict__ s, unsigned short* __restrict__ s1)
{
    const int m0 = blockIdx.x * 64;
    const int batch = m0 >> 9;
    const int t = threadIdx.x, w = t >> 6, lane = t & 63;
    const int fm = lane & 15, quad = lane >> 4;
    const int mrow = m0 + w * 16 + fm;
    f4v acc[4];
#pragma unroll
    for (int j = 0; j < 4; ++j) acc[j] = (f4v){0.f, 0.f, 0.f, 0.f};
    for (int k0 = 0; k0 < H_; k0 += 32) {
        const float* ap = &c[(size_t)mrow * H_ + k0 + quad * 8];
        float4 a0 = *(const float4*)ap, a1 = *(const float4*)(ap + 4);
        float xs[8] = {a0.x, a0.y, a0.z, a0.w, a1.x, a1.y, a1.z, a1.w};
        s8v fah, fal;
#pragma unroll
        for (int j = 0; j < 8; ++j) { unsigned short h, l; split2(xs[j], h, l); fah[j] = (short)h; fal[j] = (short)l; }
#pragma unroll
        for (int tn = 0; tn < 4; ++tn) {
            const size_t bo = (size_t)(batch * QL_ + tn * 16 + fm) * H_ + k0 + quad * 8;
            s8v bh = *(const s8v*)&uh[bo];
            s8v bl = *(const s8v*)&ul[bo];
            acc[tn] = __builtin_amdgcn_mfma_f32_16x16x32_bf16(fah, bh, acc[tn], 0, 0, 0);
            acc[tn] = __builtin_amdgcn_mfma_f32_16x16x32_bf16(fah, bl, acc[tn], 0, 0, 0);
            acc[tn] = __builtin_amdgcn_mfma_f32_16x16x32_bf16(fal, bh, acc[tn], 0, 0, 0);
        }
    }
    // epilogue: rows m0 + w*16 + quad*4 + r, cols tn*16 + fm
    float bet[4]; int qm[4];
#pragma unroll
    for (int tn = 0; tn < 4; ++tn) {
        const int col = tn * 16 + fm;
        bet[tn] = beta[batch * QL_ + col];
        qm[tn]  = q_mask[batch * QL_ + col];
    }
    const int rowb = m0 + w * 16 + quad * 4;
#pragma unroll
    for (int r = 0; r < 4; ++r) {
        float x[4], xm[4];
#pragma unroll
        for (int tn = 0; tn < 4; ++tn) {
            x[tn] = acc[tn][r] + bet[tn];
            s[(size_t)(rowb + r) * QL_ + tn * 16 + fm] = x[tn];   // raw s for col-softmax
            xm[tn] = qm[tn] ? x[tn] : -1e30f;
        }
        float mx = fmaxf(fmaxf(xm[0], xm[1]), fmaxf(xm[2], xm[3]));
#pragma unroll
        for (int o = 8; o; o >>= 1) mx = fmaxf(mx, __shfl_xor(mx, o));
        float e[4], sm = 0.f;
#pragma unroll
        for (int tn = 0; tn < 4; ++tn) { e[tn] = __expf(xm[tn] - mx); sm += e[tn]; }
#pragma unroll
        for (int o = 8; o; o >>= 1) sm += __shfl_xor(sm, o);
        const float inv = 1.f / sm;
#pragma unroll
        for (int tn = 0; tn < 4; ++tn)
            s1[(size_t)(rowb + r) * QL_ + tn * 16 + fm] = bf16_rne(e[tn] * inv);
    }
}

// ---------- K6: s2^T = col softmax (c dim) -> bf16 [b][q][c] ----------
__global__ __launch_bounds__(256) void k_sm_cols(const float* __restrict__ s,
    const int* __restrict__ c_mask, unsigned short* __restrict__ s2t)
{
    __shared__ float red[4];
    const int b = blockIdx.x >> 6, qi = blockIdx.x & 63;
    const int t = threadIdx.x;
    const float* sb = s + (size_t)b * CL_ * QL_ + qi;
    const int* cm = c_mask + b * CL_;
    float x0 = cm[t] ? sb[(size_t)t * QL_] : -1e30f;
    float x1 = cm[t + 256] ? sb[(size_t)(t + 256) * QL_] : -1e30f;
    float m = fmaxf(x0, x1);
#pragma unroll
    for (int o = 32; o; o >>= 1) m = fmaxf(m, __shfl_xor(m, o));
    if ((t & 63) == 0) red[t >> 6] = m;
    __syncthreads();
    m = fmaxf(fmaxf(red[0], red[1]), fmaxf(red[2], red[3]));
    __syncthreads();
    float e0 = __expf(x0 - m), e1 = __expf(x1 - m);
    float sm = e0 + e1;
#pragma unroll
    for (int o = 32; o; o >>= 1) sm += __shfl_xor(sm, o);
    if ((t & 63) == 0) red[t >> 6] = sm;
    __syncthreads();
    sm = red[0] + red[1] + red[2] + red[3];
    float inv = 1.f / sm;
    unsigned short* o = s2t + ((size_t)b * QL_ + qi) * CL_;
    o[t]       = bf16_rne(e0 * inv);
    o[t + 256] = bf16_rne(e1 * inv);
}

// ---------- K7: tt[b][h][q] = (s2^T @ c)^T (bf16 MFMA, c via LDS transpose) ----------
__global__ __launch_bounds__(256) void k_t(const unsigned short* __restrict__ s2t,
    const float* __restrict__ c, unsigned short* __restrict__ tt)
{
    __shared__ unsigned short Bs[64][40];
    const int h0 = blockIdx.x * 64, b = blockIdx.y;
    const int t = threadIdx.x, w = t >> 6, lane = t & 63;
    const int fm = lane & 15, quad = lane >> 4;
    const int dd = t >> 3, hc = (t & 7) * 8;
    f4v acc[4];
#pragma unroll
    for (int j = 0; j < 4; ++j) acc[j] = (f4v){0.f, 0.f, 0.f, 0.f};
    for (int d0 = 0; d0 < CL_; d0 += 32) {
        const float* cp = &c[((size_t)b * CL_ + d0 + dd) * H_ + h0 + hc];
        float4 v0 = *(const float4*)cp, v1 = *(const float4*)(cp + 4);
        float xs[8] = {v0.x, v0.y, v0.z, v0.w, v1.x, v1.y, v1.z, v1.w};
        __syncthreads();
#pragma unroll
        for (int j = 0; j < 8; ++j) Bs[hc + j][dd] = bf16_rne(xs[j]);
        __syncthreads();
        s8v fb = *(const s8v*)&Bs[w * 16 + fm][quad * 8];
#pragma unroll
        for (int tm = 0; tm < 4; ++tm) {
            s8v fa = *(const s8v*)&s2t[((size_t)b * QL_ + tm * 16 + fm) * CL_ + d0 + quad * 8];
            acc[tm] = __builtin_amdgcn_mfma_f32_16x16x32_bf16(fa, fb, acc[tm], 0, 0, 0);
        }
    }
#pragma unroll
    for (int tm = 0; tm < 4; ++tm) {
        ushort4 o;
        o.x = bf16_rne(acc[tm][0]); o.y = bf16_rne(acc[tm][1]);
        o.z = bf16_rne(acc[tm][2]); o.w = bf16_rne(acc[tm][3]);
        *(ushort4*)&tt[((size_t)b * H_ + h0 + w * 16 + fm) * QL_ + tm * 16 + quad * 4] = o;
    }
}

// ---------- K8: finalize (transposed D: rows=h, cols=crow -> float4 stores) ----------
// grid (12, 4, 16); block: 64 h x 128 crow; wave: 64 h x 32 crow.
__global__ __launch_bounds__(256) void k_fin(const unsigned short* __restrict__ s1,
    const unsigned short* __restrict__ qt, const unsigned short* __restrict__ tt,
    const float* __restrict__ c, float* __restrict__ out)
{
    const int h0 = blockIdx.x * 64;
    const int c0 = blockIdx.y * 128;
    const int b  = blockIdx.z;
    const int t = threadIdx.x, w = t >> 6, lane = t & 63;
    const int fm = lane & 15, quad = lane >> 4;
    const int cbase = c0 + w * 32;
    f4v aa[4][2], bb[4][2];   // [tm=h-tile][tn=crow-tile]
#pragma unroll
    for (int i = 0; i < 4; ++i)
#pragma unroll
        for (int j = 0; j < 2; ++j) { aa[i][j] = (f4v){0.f, 0.f, 0.f, 0.f}; bb[i][j] = aa[i][j]; }
#pragma unroll
    for (int ks = 0; ks < 2; ++ks) {
        s8v fq[4], ft[4], fs[2];
#pragma unroll
        for (int tm = 0; tm < 4; ++tm) {
            size_t ro = ((size_t)b * H_ + h0 + tm * 16 + fm) * QL_ + ks * 32 + quad * 8;
            fq[tm] = *(const s8v*)&qt[ro];
            ft[tm] = *(const s8v*)&tt[ro];
        }
#pragma unroll
        for (int tn = 0; tn < 2; ++tn)
            fs[tn] = *(const s8v*)&s1[(size_t)(b * CL_ + cbase + tn * 16 + fm) * QL_ + ks * 32 + quad * 8];
#pragma unroll
        for (int tm = 0; tm < 4; ++tm)
#pragma unroll
            for (int tn = 0; tn < 2; ++tn) {
                aa[tm][tn] = __builtin_amdgcn_mfma_f32_16x16x32_bf16(fq[tm], fs[tn], aa[tm][tn], 0, 0, 0);
                bb[tm][tn] = __builtin_amdgcn_mfma_f32_16x16x32_bf16(ft[tm], fs[tn], bb[tm][tn], 0, 0, 0);
            }
    }
    // D row = h0 + tm*16 + quad*4 + reg, col = cbase + tn*16 + fm
#pragma unroll
    for (int tn = 0; tn < 2; ++tn) {
        const int crow = cbase + tn * 16 + fm;
        const float* cb = c + ((size_t)b * CL_ + crow) * H_;
        float* ob = out + ((size_t)b * CL_ + crow) * (4 * H_);
#pragma unroll
        for (int tm = 0; tm < 4; ++tm) {
            const int h = h0 + tm * 16 + quad * 4;
            float4 cv = *(const float4*)&cb[h];
            f4v av = aa[tm][tn], bv = bb[tm][tn];
            float4 a4  = make_float4(av[0], av[1], av[2], av[3]);
            float4 b4  = make_float4(bv[0], bv[1], bv[2], bv[3]);
            float4 ca4 = make_float4(cv.x * a4.x, cv.y * a4.y, cv.z * a4.z, cv.w * a4.w);
            float4 cb4 = make_float4(cv.x * b4.x, cv.y * b4.y, cv.z * b4.z, cv.w * b4.w);
            *(float4*)&ob[h]            = cv;
            *(float4*)&ob[H_ + h]       = a4;
            *(float4*)&ob[2 * H_ + h]   = ca4;
            *(float4*)&ob[3 * H_ + h]   = cb4;
        }
    }
}

extern "C" void kernel_launch(void* const* d_in, const int* in_sizes, int n_in,
                              void* d_out, int out_size, void* d_ws, size_t ws_size,
                              hipStream_t stream) {
    const float* c      = (const float*)d_in[0];
    const float* q      = (const float*)d_in[1];
    const int*   c_mask = (const int*)d_in[2];
    const int*   q_mask = (const int*)d_in[3];
    const float* W      = (const float*)d_in[4];
    const float* bias   = (const float*)d_in[5];
    float* out = (float*)d_out;

    char* base = (char*)d_ws;
    unsigned short* wth  = (unsigned short*)(base);              // 1179648
    unsigned short* wtl  = (unsigned short*)(base + 1179648);    // 1179648
    unsigned short* qt   = (unsigned short*)(base + 2359296);    // 1572864
    unsigned short* uh   = (unsigned short*)(base + 3932160);    // 1572864
    unsigned short* ul   = (unsigned short*)(base + 5505024);    // 1572864
    float*          beta = (float*)(base + 7077888);             // 4096
    float*          s    = (float*)(base + 7081984);             // 2097152
    unsigned short* s1   = (unsigned short*)(base + 9179136);    // 1048576
    unsigned short* s2t  = (unsigned short*)(base + 10227712);   // 1048576
    unsigned short* tt   = (unsigned short*)(base + 11276288);   // 1572864

    dim3 blk(256);
    k_tw     <<<dim3(12, 12),    blk, 0, stream>>>(W, wth, wtl);
    k_tq     <<<dim3(12, B_),    blk, 0, stream>>>(q, qt);
    k_beta   <<<dim3(256),       blk, 0, stream>>>(q, bias, beta);
    k_u      <<<dim3(16, 12),    blk, 0, stream>>>(q, wth, wtl, uh, ul);
    k_s      <<<dim3(128),       blk, 0, stream>>>(c, uh, ul, beta, q_mask, s, s1);
    k_sm_cols<<<dim3(B_ * QL_),  blk, 0, stream>>>(s, c_mask, s2t);
    k_t      <<<dim3(12, B_),    blk, 0, stream>>>(s2t, c, tt);
    k_fin    <<<dim3(12, 4, B_), blk, 0, stream>>>(s1, qt, tt, c, out);
}